// Round 3
// baseline (38787.634 us; speedup 1.0000x reference)
//
#include <hip/hip_runtime.h>

#define T_STEPS 65536
#define NIN 99
#define HID 64
#define G4 256   // 4*HID gates
#define TS 128   // timesteps per block in the projection kernel
#define PF 8     // prefetch depth (steps) in the recurrence kernel

__device__ __forceinline__ float frcp(float x) { return __builtin_amdgcn_rcpf(x); }
__device__ __forceinline__ float fexp(float x) { return __expf(x); }
__device__ __forceinline__ float sigmoid_f(float x) { return frcp(1.0f + fexp(-x)); }
__device__ __forceinline__ float tanh_f(float x) {
    float ax = fabsf(x);
    float e  = fexp(2.0f * ax);                 // inf for large ax fine: rcp(inf)=0
    float r  = 1.0f - 2.0f * frcp(e + 1.0f);
    return copysignf(r, x);
}
// wave-uniform broadcast of lane `lane`'s value via readlane (VALU, not LDS pipe)
__device__ __forceinline__ float bcast(float v, int lane) {
    return __int_as_float(__builtin_amdgcn_readlane(__float_as_int(v), lane));
}

// ---------------- Kernel 1: xz[t][g] = W_ih[g] . x[t] + b_ih[g] + b_hh[g] ----------------
// __launch_bounds__(256,1): 1 wave/EU -> full VGPR budget so w[99] stays resident.
__global__ __launch_bounds__(256, 1) void xz_kernel(
    const float* __restrict__ x, const float* __restrict__ W_ih,
    const float* __restrict__ b_ih, const float* __restrict__ b_hh,
    float* __restrict__ xz) {
    __shared__ __align__(16) float xs[TS * 100];   // padded rows: 400 B stride
    const int g  = threadIdx.x;
    const int t0 = blockIdx.x * TS;

    for (int i = g; i < TS * NIN; i += 256) {
        int tl = i / NIN;
        int j  = i - tl * NIN;
        xs[tl * 100 + j] = x[(size_t)t0 * NIN + i];
    }

    float w[NIN];
#pragma unroll
    for (int j = 0; j < NIN; ++j) w[j] = W_ih[g * NIN + j];
    const float bias = b_ih[g] + b_hh[g];
    __syncthreads();

    for (int tl = 0; tl < TS; ++tl) {
        const float* xr = &xs[tl * 100];
        float a0 = bias, a1 = 0.f, a2 = 0.f, a3 = 0.f;
#pragma unroll
        for (int j4 = 0; j4 < 24; ++j4) {
            float4 xv = *(const float4*)(xr + 4 * j4);
            a0 = fmaf(w[4 * j4 + 0], xv.x, a0);
            a1 = fmaf(w[4 * j4 + 1], xv.y, a1);
            a2 = fmaf(w[4 * j4 + 2], xv.z, a2);
            a3 = fmaf(w[4 * j4 + 3], xv.w, a3);
        }
        a0 = fmaf(w[96], xr[96], a0);
        a1 = fmaf(w[97], xr[97], a1);
        a2 = fmaf(w[98], xr[98], a2);
        xz[(size_t)(t0 + tl) * G4 + g] = (a0 + a1) + (a2 + a3);
    }
}

// ---------------- Kernel 2: sequential LSTM recurrence + MLP head (single block) ----------------
// 4 waves; thread tid computes gate row tid. W_hh row held in 16 NAMED float4
// registers (no array -> cannot be demoted to scratch). Every wave redundantly
// keeps h[l], c[l] in lane registers; h broadcast via v_readlane; one barrier
// per step with double-buffered gate exchange.
__global__ __launch_bounds__(256, 1) void lstm_kernel(
    const float* __restrict__ xz, const float* __restrict__ W_hh,
    const float* __restrict__ W1, const float* __restrict__ W2,
    const float* __restrict__ b2, float* __restrict__ out) {
    __shared__ float gbuf[2][G4];
    __shared__ float hfin[HID];
    __shared__ float hbuf[32];
    const int tid = threadIdx.x;
    const int l   = tid & 63;
    const int wv  = tid >> 6;

    // gate-row weights: 16 named float4s (64 VGPRs, guaranteed resident)
    const float4* wp = (const float4*)(W_hh + tid * HID);   // 256B-aligned
    float4 w0 = wp[0],  w1 = wp[1],  w2 = wp[2],  w3 = wp[3];
    float4 w4 = wp[4],  w5 = wp[5],  w6 = wp[6],  w7 = wp[7];
    float4 w8 = wp[8],  w9 = wp[9],  w10 = wp[10], w11 = wp[11];
    float4 w12 = wp[12], w13 = wp[13], w14 = wp[14], w15 = wp[15];

    float h = 0.0f, c = 0.0f;      // lane l of every wave: h[l], c[l] (redundant copies)

    const float* zp = xz + tid;    // coalesced column of xz
    float zcur[PF], znxt[PF];
#pragma unroll
    for (int p = 0; p < PF; ++p) { zcur[p] = zp[(size_t)p * G4]; znxt[p] = 0.0f; }

    const bool tanh_gate = (wv == 2);   // gate 'g' block

#define FMA4(W, B)                                   \
    a0 = fmaf(W.x, bcast(h, (B) + 0), a0);           \
    a1 = fmaf(W.y, bcast(h, (B) + 1), a1);           \
    a2 = fmaf(W.z, bcast(h, (B) + 2), a2);           \
    a3 = fmaf(W.w, bcast(h, (B) + 3), a3);

    for (int tb = 0; tb < T_STEPS; tb += PF) {
        if (tb + PF < T_STEPS) {
#pragma unroll
            for (int p = 0; p < PF; ++p) znxt[p] = zp[(size_t)(tb + PF + p) * G4];
        }
#pragma unroll
        for (int u = 0; u < PF; ++u) {
            float a0 = zcur[u], a1 = 0.f, a2 = 0.f, a3 = 0.f;
            FMA4(w0, 0)   FMA4(w1, 4)   FMA4(w2, 8)   FMA4(w3, 12)
            FMA4(w4, 16)  FMA4(w5, 20)  FMA4(w6, 24)  FMA4(w7, 28)
            FMA4(w8, 32)  FMA4(w9, 36)  FMA4(w10, 40) FMA4(w11, 44)
            FMA4(w12, 48) FMA4(w13, 52) FMA4(w14, 56) FMA4(w15, 60)
            float z = (a0 + a1) + (a2 + a3);
            float a = tanh_gate ? tanh_f(z) : sigmoid_f(z);

            float* buf = gbuf[u & 1];
            buf[tid] = a;
            __syncthreads();
            float iv = buf[l];
            float fv = buf[64 + l];
            float gv = buf[128 + l];
            float ov = buf[192 + l];
            c = fmaf(fv, c, iv * gv);
            h = ov * tanh_f(c);
        }
#pragma unroll
        for (int p = 0; p < PF; ++p) zcur[p] = znxt[p];
    }
#undef FMA4

    // head: out = W2 @ relu(W1 @ relu(h_T)) + b2
    if (tid < HID) hfin[tid] = h;
    __syncthreads();
    if (tid < 32) {
        float s = 0.0f;
#pragma unroll
        for (int j = 0; j < HID; ++j) s += W1[tid * HID + j] * fmaxf(hfin[j], 0.0f);
        hbuf[tid] = fmaxf(s, 0.0f);
    }
    __syncthreads();
    if (tid < 3) {
        float s = b2[tid];
#pragma unroll
        for (int j = 0; j < 32; ++j) s += W2[tid * 32 + j] * hbuf[j];
        out[tid] = s;
    }
}

extern "C" void kernel_launch(void* const* d_in, const int* in_sizes, int n_in,
                              void* d_out, int out_size, void* d_ws, size_t ws_size,
                              hipStream_t stream) {
    const float* x   = (const float*)d_in[0];
    const float* Wih = (const float*)d_in[1];
    const float* Whh = (const float*)d_in[2];
    const float* bih = (const float*)d_in[3];
    const float* bhh = (const float*)d_in[4];
    const float* W1  = (const float*)d_in[5];
    const float* W2  = (const float*)d_in[6];
    const float* b2  = (const float*)d_in[7];
    float* out = (float*)d_out;
    float* xz  = (float*)d_ws;   // T_STEPS * 256 floats = 64 MB

    xz_kernel<<<T_STEPS / TS, 256, 0, stream>>>(x, Wih, bih, bhh, xz);
    lstm_kernel<<<1, 256, 0, stream>>>(xz, Whh, W1, W2, b2, out);
}

// Round 4
// 27681.934 us; speedup vs baseline: 1.4012x; 1.4012x over previous
//
#include <hip/hip_runtime.h>

#define T_STEPS 65536
#define NIN 99
#define HID 64
#define G4 256   // 4*HID gates
#define TS 128   // timesteps per block in the projection kernel
#define PF 8     // prefetch depth (steps) in the recurrence kernel

__device__ __forceinline__ float frcp(float x) { return __builtin_amdgcn_rcpf(x); }
__device__ __forceinline__ float fexp(float x) { return __expf(x); }
__device__ __forceinline__ float sigmoid_f(float x) { return frcp(1.0f + fexp(-x)); }
__device__ __forceinline__ float tanh_f(float x) {
    float ax = fabsf(x);
    float e  = fexp(2.0f * ax);                 // inf for large ax fine: rcp(inf)=0
    float r  = 1.0f - 2.0f * frcp(e + 1.0f);
    return copysignf(r, x);
}
// wave-uniform broadcast of lane `lane`'s value via readlane (VALU, not LDS pipe)
__device__ __forceinline__ float bcast(float v, int lane) {
    return __int_as_float(__builtin_amdgcn_readlane(__float_as_int(v), lane));
}

// ---------------- Kernel 1: xz[t][g] = W_ih[g] . x[t] + b_ih[g] + b_hh[g] ----------------
__global__ __launch_bounds__(256, 1) void xz_kernel(
    const float* __restrict__ x, const float* __restrict__ W_ih,
    const float* __restrict__ b_ih, const float* __restrict__ b_hh,
    float* __restrict__ xz) {
    __shared__ __align__(16) float xs[TS * 100];   // padded rows: 400 B stride
    const int g  = threadIdx.x;
    const int t0 = blockIdx.x * TS;

    for (int i = g; i < TS * NIN; i += 256) {
        int tl = i / NIN;
        int j  = i - tl * NIN;
        xs[tl * 100 + j] = x[(size_t)t0 * NIN + i];
    }

    float w[NIN];
#pragma unroll
    for (int j = 0; j < NIN; ++j) w[j] = W_ih[g * NIN + j];
    const float bias = b_ih[g] + b_hh[g];
    __syncthreads();

    for (int tl = 0; tl < TS; ++tl) {
        const float* xr = &xs[tl * 100];
        float a0 = bias, a1 = 0.f, a2 = 0.f, a3 = 0.f;
#pragma unroll
        for (int j4 = 0; j4 < 24; ++j4) {
            float4 xv = *(const float4*)(xr + 4 * j4);
            a0 = fmaf(w[4 * j4 + 0], xv.x, a0);
            a1 = fmaf(w[4 * j4 + 1], xv.y, a1);
            a2 = fmaf(w[4 * j4 + 2], xv.z, a2);
            a3 = fmaf(w[4 * j4 + 3], xv.w, a3);
        }
        a0 = fmaf(w[96], xr[96], a0);
        a1 = fmaf(w[97], xr[97], a1);
        a2 = fmaf(w[98], xr[98], a2);
        xz[(size_t)(t0 + tl) * G4 + g] = (a0 + a1) + (a2 + a3);
    }
}

// ---------------- Kernel 2: sequential LSTM recurrence + MLP head (single block) ----------------
// 4 waves; thread tid computes gate row tid. W_hh row held in 16 float4s that
// are PINNED into VGPRs via an empty asm re-definition: the invariant global
// loads were being rematerialized into the loop by the scheduler (R2/R3:
// VGPR_Count=48, identical timing). An asm output cannot be rematerialized.
__global__ __launch_bounds__(256, 1) __attribute__((amdgpu_waves_per_eu(1)))
void lstm_kernel(
    const float* __restrict__ xz, const float* __restrict__ W_hh,
    const float* __restrict__ W1, const float* __restrict__ W2,
    const float* __restrict__ b2, float* __restrict__ out) {
    __shared__ float gbuf[2][G4];
    __shared__ float hfin[HID];
    __shared__ float hbuf[32];
    const int tid = threadIdx.x;
    const int l   = tid & 63;
    const int wv  = tid >> 6;

    // gate-row weights: 16 float4s (64 VGPRs), pinned resident
    const float4* wp = (const float4*)(W_hh + tid * HID);   // 256B-aligned
    float4 w0 = wp[0],  w1 = wp[1],  w2 = wp[2],  w3 = wp[3];
    float4 w4 = wp[4],  w5 = wp[5],  w6 = wp[6],  w7 = wp[7];
    float4 w8 = wp[8],  w9 = wp[9],  w10 = wp[10], w11 = wp[11];
    float4 w12 = wp[12], w13 = wp[13], w14 = wp[14], w15 = wp[15];

#define PIN4(v) asm volatile("" : "+v"(v.x), "+v"(v.y), "+v"(v.z), "+v"(v.w))
    PIN4(w0);  PIN4(w1);  PIN4(w2);  PIN4(w3);
    PIN4(w4);  PIN4(w5);  PIN4(w6);  PIN4(w7);
    PIN4(w8);  PIN4(w9);  PIN4(w10); PIN4(w11);
    PIN4(w12); PIN4(w13); PIN4(w14); PIN4(w15);
#undef PIN4

    float h = 0.0f, c = 0.0f;      // lane l of every wave: h[l], c[l] (redundant copies)

    const float* zp = xz + tid;    // coalesced column of xz
    float zcur[PF], znxt[PF];
#pragma unroll
    for (int p = 0; p < PF; ++p) { zcur[p] = zp[(size_t)p * G4]; znxt[p] = 0.0f; }

    const bool tanh_gate = (wv == 2);   // gate 'g' block

#define FMA4(W, B)                                   \
    a0 = fmaf(W.x, bcast(h, (B) + 0), a0);           \
    a1 = fmaf(W.y, bcast(h, (B) + 1), a1);           \
    a2 = fmaf(W.z, bcast(h, (B) + 2), a2);           \
    a3 = fmaf(W.w, bcast(h, (B) + 3), a3);

    for (int tb = 0; tb < T_STEPS; tb += PF) {
        if (tb + PF < T_STEPS) {
#pragma unroll
            for (int p = 0; p < PF; ++p) znxt[p] = zp[(size_t)(tb + PF + p) * G4];
        }
#pragma unroll
        for (int u = 0; u < PF; ++u) {
            float a0 = zcur[u], a1 = 0.f, a2 = 0.f, a3 = 0.f;
            FMA4(w0, 0)   FMA4(w1, 4)   FMA4(w2, 8)   FMA4(w3, 12)
            FMA4(w4, 16)  FMA4(w5, 20)  FMA4(w6, 24)  FMA4(w7, 28)
            FMA4(w8, 32)  FMA4(w9, 36)  FMA4(w10, 40) FMA4(w11, 44)
            FMA4(w12, 48) FMA4(w13, 52) FMA4(w14, 56) FMA4(w15, 60)
            float z = (a0 + a1) + (a2 + a3);
            float a = tanh_gate ? tanh_f(z) : sigmoid_f(z);

            float* buf = gbuf[u & 1];
            buf[tid] = a;
            __syncthreads();
            float iv = buf[l];
            float fv = buf[64 + l];
            float gv = buf[128 + l];
            float ov = buf[192 + l];
            c = fmaf(fv, c, iv * gv);
            h = ov * tanh_f(c);
        }
#pragma unroll
        for (int p = 0; p < PF; ++p) zcur[p] = znxt[p];
    }
#undef FMA4

    // head: out = W2 @ relu(W1 @ relu(h_T)) + b2
    if (tid < HID) hfin[tid] = h;
    __syncthreads();
    if (tid < 32) {
        float s = 0.0f;
#pragma unroll
        for (int j = 0; j < HID; ++j) s += W1[tid * HID + j] * fmaxf(hfin[j], 0.0f);
        hbuf[tid] = fmaxf(s, 0.0f);
    }
    __syncthreads();
    if (tid < 3) {
        float s = b2[tid];
#pragma unroll
        for (int j = 0; j < 32; ++j) s += W2[tid * 32 + j] * hbuf[j];
        out[tid] = s;
    }
}

extern "C" void kernel_launch(void* const* d_in, const int* in_sizes, int n_in,
                              void* d_out, int out_size, void* d_ws, size_t ws_size,
                              hipStream_t stream) {
    const float* x   = (const float*)d_in[0];
    const float* Wih = (const float*)d_in[1];
    const float* Whh = (const float*)d_in[2];
    const float* bih = (const float*)d_in[3];
    const float* bhh = (const float*)d_in[4];
    const float* W1  = (const float*)d_in[5];
    const float* W2  = (const float*)d_in[6];
    const float* b2  = (const float*)d_in[7];
    float* out = (float*)d_out;
    float* xz  = (float*)d_ws;   // T_STEPS * 256 floats = 64 MB

    xz_kernel<<<T_STEPS / TS, 256, 0, stream>>>(x, Wih, bih, bhh, xz);
    lstm_kernel<<<1, 256, 0, stream>>>(xz, Whh, W1, W2, b2, out);
}

// Round 5
// 25803.876 us; speedup vs baseline: 1.5032x; 1.0728x over previous
//
#include <hip/hip_runtime.h>

#define T_STEPS 65536
#define NIN 99
#define HID 64
#define G4 256   // 4*HID gates
#define TS 128   // timesteps per block in the projection kernel
#define PF 8     // prefetch depth (steps) in the recurrence kernel

__device__ __forceinline__ float frcp(float x) { return __builtin_amdgcn_rcpf(x); }
__device__ __forceinline__ float fexp(float x) { return __expf(x); }
__device__ __forceinline__ float sigmoid_f(float x) { return frcp(1.0f + fexp(-x)); }
__device__ __forceinline__ float tanh_f(float x) {
    float ax = fabsf(x);
    float e  = fexp(2.0f * ax);                 // inf for large ax fine: rcp(inf)=0
    float r  = 1.0f - 2.0f * frcp(e + 1.0f);
    return copysignf(r, x);
}
// wave-uniform broadcast of lane `lane`'s value via readlane (VALU->SGPR)
__device__ __forceinline__ float bcast(float v, int lane) {
    return __int_as_float(__builtin_amdgcn_readlane(__float_as_int(v), lane));
}

// ---------------- Kernel 1: xz[t][g] = W_ih[g] . x[t] + b_ih[g] + b_hh[g] ----------------
__global__ __launch_bounds__(256, 1) void xz_kernel(
    const float* __restrict__ x, const float* __restrict__ W_ih,
    const float* __restrict__ b_ih, const float* __restrict__ b_hh,
    float* __restrict__ xz) {
    __shared__ __align__(16) float xs[TS * 100];   // padded rows: 400 B stride
    const int g  = threadIdx.x;
    const int t0 = blockIdx.x * TS;

    for (int i = g; i < TS * NIN; i += 256) {
        int tl = i / NIN;
        int j  = i - tl * NIN;
        xs[tl * 100 + j] = x[(size_t)t0 * NIN + i];
    }

    float w[NIN];
#pragma unroll
    for (int j = 0; j < NIN; ++j) w[j] = W_ih[g * NIN + j];
    const float bias = b_ih[g] + b_hh[g];
    __syncthreads();

    for (int tl = 0; tl < TS; ++tl) {
        const float* xr = &xs[tl * 100];
        float a0 = bias, a1 = 0.f, a2 = 0.f, a3 = 0.f;
#pragma unroll
        for (int j4 = 0; j4 < 24; ++j4) {
            float4 xv = *(const float4*)(xr + 4 * j4);
            a0 = fmaf(w[4 * j4 + 0], xv.x, a0);
            a1 = fmaf(w[4 * j4 + 1], xv.y, a1);
            a2 = fmaf(w[4 * j4 + 2], xv.z, a2);
            a3 = fmaf(w[4 * j4 + 3], xv.w, a3);
        }
        a0 = fmaf(w[96], xr[96], a0);
        a1 = fmaf(w[97], xr[97], a1);
        a2 = fmaf(w[98], xr[98], a2);
        xz[(size_t)(t0 + tl) * G4 + g] = (a0 + a1) + (a2 + a3);
    }
}

// ---------------- Kernel 2: split-K LSTM recurrence (single block) ----------------
// Wave wv owns k-chunk [16wv,16wv+16). Thread (wv,l) computes the partial dot
// of gates 4l..4l+3 over its chunk: 16 readlane broadcasts + 64 fma (4 acc
// chains). Partials reduced cross-wave via LDS; activation is wave-uniform on
// the reduce thread (gate type = tid>>6); gate exchange via second LDS buffer;
// h,c replicated per-wave in lane registers. Double-buffered, 2 barriers/step.
__global__ __launch_bounds__(256, 1) __attribute__((amdgpu_waves_per_eu(1)))
void lstm_kernel(
    const float* __restrict__ xz, const float* __restrict__ W_hh,
    const float* __restrict__ W1, const float* __restrict__ W2,
    const float* __restrict__ b2, float* __restrict__ out) {
    __shared__ __align__(16) float pbuf[2][4][G4];   // [parity][k-chunk][gate]
    __shared__ float gbuf[2][G4];                    // [parity][gate]
    __shared__ float hfin[HID];
    __shared__ float hbuf[32];
    const int tid = threadIdx.x;
    const int l   = tid & 63;
    const int wv  = tid >> 6;
    const int kbase = 16 * wv;                       // this wave's k-chunk base
    const int sb  = __builtin_amdgcn_readfirstlane(kbase);

    // weights: rows 4l..4l+3, cols [kbase, kbase+16)  -> 16 float4s, pinned
    const float* Wb = W_hh + (4 * l) * HID + kbase;  // row stride 64 floats
    float4 w00 = *(const float4*)(Wb +   0), w01 = *(const float4*)(Wb +   4),
           w02 = *(const float4*)(Wb +   8), w03 = *(const float4*)(Wb +  12);
    float4 w10 = *(const float4*)(Wb +  64), w11 = *(const float4*)(Wb +  68),
           w12 = *(const float4*)(Wb +  72), w13 = *(const float4*)(Wb +  76);
    float4 w20 = *(const float4*)(Wb + 128), w21 = *(const float4*)(Wb + 132),
           w22 = *(const float4*)(Wb + 136), w23 = *(const float4*)(Wb + 140);
    float4 w30 = *(const float4*)(Wb + 192), w31 = *(const float4*)(Wb + 196),
           w32 = *(const float4*)(Wb + 200), w33 = *(const float4*)(Wb + 204);

#define PIN4(v) asm volatile("" : "+v"(v.x), "+v"(v.y), "+v"(v.z), "+v"(v.w))
    PIN4(w00); PIN4(w01); PIN4(w02); PIN4(w03);
    PIN4(w10); PIN4(w11); PIN4(w12); PIN4(w13);
    PIN4(w20); PIN4(w21); PIN4(w22); PIN4(w23);
    PIN4(w30); PIN4(w31); PIN4(w32); PIN4(w33);
#undef PIN4

    float h = 0.0f, c = 0.0f;       // lane l of every wave: h[l], c[l]

    const float* zp = xz + tid;     // coalesced column of xz (gate = tid)
    float zcur[PF], znxt[PF];
#pragma unroll
    for (int p = 0; p < PF; ++p) { zcur[p] = zp[(size_t)p * G4]; znxt[p] = 0.0f; }

    const bool tanh_gate = (wv == 2);   // reduce-thread tid owns gate tid; type = tid>>6

    // one j4 block: broadcast 4 h values of this wave's chunk, 16 fma
#define STEP_J4(J4, W0, W1_, W2_, W3_)                                          \
    {   float hx0 = bcast(h, sb + 4 * J4 + 0);                                  \
        float hx1 = bcast(h, sb + 4 * J4 + 1);                                  \
        float hx2 = bcast(h, sb + 4 * J4 + 2);                                  \
        float hx3 = bcast(h, sb + 4 * J4 + 3);                                  \
        a0 = fmaf(W0.x, hx0, a0); a0 = fmaf(W0.y, hx1, a0);                     \
        a0 = fmaf(W0.z, hx2, a0); a0 = fmaf(W0.w, hx3, a0);                     \
        a1 = fmaf(W1_.x, hx0, a1); a1 = fmaf(W1_.y, hx1, a1);                   \
        a1 = fmaf(W1_.z, hx2, a1); a1 = fmaf(W1_.w, hx3, a1);                   \
        a2 = fmaf(W2_.x, hx0, a2); a2 = fmaf(W2_.y, hx1, a2);                   \
        a2 = fmaf(W2_.z, hx2, a2); a2 = fmaf(W2_.w, hx3, a2);                   \
        a3 = fmaf(W3_.x, hx0, a3); a3 = fmaf(W3_.y, hx1, a3);                   \
        a3 = fmaf(W3_.z, hx2, a3); a3 = fmaf(W3_.w, hx3, a3); }

    for (int tb = 0; tb < T_STEPS; tb += PF) {
        if (tb + PF < T_STEPS) {
#pragma unroll
            for (int p = 0; p < PF; ++p) znxt[p] = zp[(size_t)(tb + PF + p) * G4];
        }
#pragma unroll
        for (int u = 0; u < PF; ++u) {
            const int par = u & 1;
            // phase 1: partial dots for gates 4l..4l+3 over k-chunk [sb, sb+16)
            float a0 = 0.f, a1 = 0.f, a2 = 0.f, a3 = 0.f;
            STEP_J4(0, w00, w10, w20, w30)
            STEP_J4(1, w01, w11, w21, w31)
            STEP_J4(2, w02, w12, w22, w32)
            STEP_J4(3, w03, w13, w23, w33)
            *(float4*)(&pbuf[par][wv][4 * l]) = make_float4(a0, a1, a2, a3);
            __syncthreads();

            // phase 2a: reduce 4 partials + xz, activate (gate = tid, wave-uniform type)
            const float* pb = &pbuf[par][0][0];
            float s = zcur[u] + ((pb[tid] + pb[G4 + tid]) + (pb[2 * G4 + tid] + pb[3 * G4 + tid]));
            float a = tanh_gate ? tanh_f(s) : sigmoid_f(s);
            gbuf[par][tid] = a;
            __syncthreads();

            // phase 2b: replicated c/h update for index l
            const float* gb = &gbuf[par][0];
            float iv = gb[l];
            float fv = gb[64 + l];
            float gv = gb[128 + l];
            float ov = gb[192 + l];
            c = fmaf(fv, c, iv * gv);
            h = ov * tanh_f(c);
        }
#pragma unroll
        for (int p = 0; p < PF; ++p) zcur[p] = znxt[p];
    }
#undef STEP_J4

    // head: out = W2 @ relu(W1 @ relu(h_T)) + b2
    if (tid < HID) hfin[tid] = h;
    __syncthreads();
    if (tid < 32) {
        float s = 0.0f;
#pragma unroll
        for (int j = 0; j < HID; ++j) s += W1[tid * HID + j] * fmaxf(hfin[j], 0.0f);
        hbuf[tid] = fmaxf(s, 0.0f);
    }
    __syncthreads();
    if (tid < 3) {
        float s = b2[tid];
#pragma unroll
        for (int j = 0; j < 32; ++j) s += W2[tid * 32 + j] * hbuf[j];
        out[tid] = s;
    }
}

extern "C" void kernel_launch(void* const* d_in, const int* in_sizes, int n_in,
                              void* d_out, int out_size, void* d_ws, size_t ws_size,
                              hipStream_t stream) {
    const float* x   = (const float*)d_in[0];
    const float* Wih = (const float*)d_in[1];
    const float* Whh = (const float*)d_in[2];
    const float* bih = (const float*)d_in[3];
    const float* bhh = (const float*)d_in[4];
    const float* W1  = (const float*)d_in[5];
    const float* W2  = (const float*)d_in[6];
    const float* b2  = (const float*)d_in[7];
    float* out = (float*)d_out;
    float* xz  = (float*)d_ws;   // T_STEPS * 256 floats = 64 MB

    xz_kernel<<<T_STEPS / TS, 256, 0, stream>>>(x, Wih, bih, bhh, xz);
    lstm_kernel<<<1, 256, 0, stream>>>(xz, Whh, W1, W2, b2, out);
}